// Round 15
// baseline (192.041 us; speedup 1.0000x reference)
//
#include <hip/hip_runtime.h>

// TsSub: out[b, p, t] = x[b, I[p], t*10] - x[b, J[p], t*10]
// x: (256, 64, 2000) f32, out: (256, 2016, 200) f32, (I,J)=triu_indices(64,k=1)
//
// R15 = R13 (one block/batch, 1x amplification, nt vec4 loads, nt stores)
// + T14 async-STAGE overlap: half0 staged to LDS; half1 issued into 28 VGPRs
// right AFTER the first barrier (no barrier between issue and use -> no
// vmcnt(0) drain); emit half0 hides half1's read; extract regs->LDS; emit
// half1. Registers statically indexed (full unroll) to avoid scratch.

#define NF     64
#define T_IN   2000
#define NPAIR  2016
#define NB     256
#define RF4    500     // vec4 per x row
#define TV4    50      // vec4 per out row
#define HV4    25      // vec4 per half out row
#define NT     1024
#define HALF   (NF * 100)   // 6400 samples per half
#define NIT    7            // ceil(HALF / NT)

typedef float fx4 __attribute__((ext_vector_type(4)));

__global__ __launch_bounds__(NT)
void ts_sub_pipe2(const float* __restrict__ xf, fx4* __restrict__ out) {
    __shared__ __attribute__((aligned(16))) float bufA[HALF];  // 25.6 KB
    __shared__ __attribute__((aligned(16))) float bufB[HALF];  // 25.6 KB
    __shared__ unsigned char pi[NPAIR];
    __shared__ unsigned char pj[NPAIR];

    const int tid = threadIdx.x;
    const int b   = blockIdx.x;
    const fx4* __restrict__ xv =
        reinterpret_cast<const fx4*>(xf + (size_t)b * (NF * T_IN));

    // --- pair table (2 iters/thread) ---
    for (int p = tid; p < NPAIR; p += NT) {
        float d = 16129.0f - 8.0f * (float)p;          // 127^2 - 8p
        int i = (int)((127.0f - sqrtf(d)) * 0.5f);
        if (i < 0) i = 0;
        while (i > 0 && (i * (127 - i)) / 2 > p) --i;
        while (((i + 1) * (126 - i)) / 2 <= p) ++i;
        pi[p] = (unsigned char)i;
        pj[p] = (unsigned char)(p - (i * (127 - i)) / 2 + i + 1);
    }

    // --- stage half0 (k<100): nt vec4 load, extract, LDS write ---
    // sample k: vec4 m = 5*(k>>1)+2*(k&1), comp = (k&1) ? .z : .x
    #pragma unroll
    for (int it = 0; it < NIT; ++it) {
        int idx = it * NT + tid;
        if (it < 6 || idx < HALF) {
            int row = idx / 100;
            int kk  = idx - row * 100;
            fx4 v = __builtin_nontemporal_load(
                        &xv[row * RF4 + 5 * (kk >> 1) + 2 * (kk & 1)]);
            bufA[idx] = (kk & 1) ? v.z : v.x;
        }
    }
    __syncthreads();   // bufA + tables ready

    // --- issue half1 loads into registers (overlap with emit half0) ---
    fx4 rr[NIT];
    #pragma unroll
    for (int it = 0; it < NIT; ++it) {
        int idx = it * NT + tid;
        if (it < 6 || idx < HALF) {
            int row = idx / 100;
            int kk  = idx - row * 100;
            rr[it] = __builtin_nontemporal_load(
                        &xv[row * RF4 + 250 + 5 * (kk >> 1) + 2 * (kk & 1)]);
        }
    }

    // --- emit half0: 2016 pair half-rows x 25 vec4, nt stores ---
    const fx4* __restrict__ sA = reinterpret_cast<const fx4*>(bufA); // stride 25
    fx4* __restrict__ ob = out + (size_t)b * (NPAIR * TV4);
    {
        int p  = tid / HV4;
        int tl = tid - p * HV4;
        for (int v = tid; v < NPAIR * HV4; v += NT) {   // 50400
            fx4 a = sA[pi[p] * HV4 + tl];
            fx4 c = sA[pj[p] * HV4 + tl];
            __builtin_nontemporal_store(a - c, &ob[(size_t)p * TV4 + tl]);
            p += 40;                           // 1024 = 40*25 + 24
            tl += 24;
            if (tl >= HV4) { tl -= HV4; ++p; }
        }
    }

    // --- extract half1 regs -> LDS (waitcnt lands here, ~30us after issue) ---
    #pragma unroll
    for (int it = 0; it < NIT; ++it) {
        int idx = it * NT + tid;
        if (it < 6 || idx < HALF) {
            bufB[idx] = (idx & 1) ? rr[it].z : rr[it].x;
        }
    }
    __syncthreads();   // bufB ready

    // --- emit half1 ---
    const fx4* __restrict__ sB = reinterpret_cast<const fx4*>(bufB);
    {
        int p  = tid / HV4;
        int tl = tid - p * HV4;
        for (int v = tid; v < NPAIR * HV4; v += NT) {
            fx4 a = sB[pi[p] * HV4 + tl];
            fx4 c = sB[pj[p] * HV4 + tl];
            __builtin_nontemporal_store(a - c, &ob[(size_t)p * TV4 + HV4 + tl]);
            p += 40;
            tl += 24;
            if (tl >= HV4) { tl -= HV4; ++p; }
        }
    }
}

extern "C" void kernel_launch(void* const* d_in, const int* in_sizes, int n_in,
                              void* d_out, int out_size, void* d_ws, size_t ws_size,
                              hipStream_t stream) {
    const float* x = (const float*)d_in[0];
    float* out = (float*)d_out;
    ts_sub_pipe2<<<dim3(NB), dim3(NT), 0, stream>>>(x, (fx4*)out);
}

// Round 16
// 100.536 us; speedup vs baseline: 1.9102x; 1.9102x over previous
//
#include <hip/hip_runtime.h>

// TsSub: out[b, p, t] = x[b, I[p], t*10] - x[b, J[p], t*10]
// x: (256, 64, 2000) f32, out: (256, 2016, 200) f32, (I,J)=triu_indices(64,k=1)
//
// R16 = R13 (one block/batch, 1x amplification, nt loads, nt stores,
// full-row emit) with load-first ordering: all 13 stage loads issued into
// registers BEFORE the pair-table build (table VALU hides load latency),
// then extract regs->LDS. Emit loop identical to R13.
// Store lesson (R7/R14/R15): never emit in sub-row chunks; nt stores need
// maximal contiguous runs (each 1024-thread pass here writes 16 KB contig).

#define NF     64
#define T_OUT  200
#define NPAIR  2016
#define NB     256
#define RF4    500     // vec4 per x row
#define TV4    50      // vec4 per out row
#define NT     1024
#define NSAMP  (NF * T_OUT)   // 12800
#define NIT    13             // ceil(12800 / 1024) = 13 (12 full + 1 partial)

typedef float fx4 __attribute__((ext_vector_type(4)));

__global__ __launch_bounds__(NT)
void ts_sub_b(const fx4* __restrict__ xv, fx4* __restrict__ out) {
    __shared__ __attribute__((aligned(16))) float sf[NSAMP];  // 51.2 KB
    __shared__ unsigned char pi[NPAIR];
    __shared__ unsigned char pj[NPAIR];

    const int tid = threadIdx.x;
    const int b   = blockIdx.x;
    const fx4* __restrict__ xb = xv + (size_t)b * (NF * RF4);

    // --- issue ALL stage loads first (sample k: vec4 m=5*(k>>1)+2*(k&1)) ---
    // idx walks tid, tid+NT, ...: row = idx/200, k = idx%200
    fx4 r0, r1, r2, r3, r4, r5, r6, r7, r8, r9, r10, r11, r12;
    {
        int row = tid / T_OUT;
        int k   = tid - row * T_OUT;
#define LOADIT(RR, IT)                                                        \
        {                                                                     \
            if (IT < 12 || (IT * NT + tid) < NSAMP) {                         \
                RR = __builtin_nontemporal_load(                              \
                         &xb[row * RF4 + 5 * (k >> 1) + 2 * (k & 1)]);        \
            }                                                                 \
            row += 5; k += 24;                     /* 1024 = 5*200 + 24 */    \
            if (k >= T_OUT) { k -= T_OUT; ++row; }                            \
        }
        LOADIT(r0, 0)  LOADIT(r1, 1)  LOADIT(r2, 2)  LOADIT(r3, 3)
        LOADIT(r4, 4)  LOADIT(r5, 5)  LOADIT(r6, 6)  LOADIT(r7, 7)
        LOADIT(r8, 8)  LOADIT(r9, 9)  LOADIT(r10, 10) LOADIT(r11, 11)
        LOADIT(r12, 12)
#undef LOADIT
    }

    // --- pair table while loads are in flight (2 iters/thread) ---
    for (int p = tid; p < NPAIR; p += NT) {
        float d = 16129.0f - 8.0f * (float)p;          // 127^2 - 8p
        int i = (int)((127.0f - sqrtf(d)) * 0.5f);
        if (i < 0) i = 0;
        while (i > 0 && (i * (127 - i)) / 2 > p) --i;
        while (((i + 1) * (126 - i)) / 2 <= p) ++i;
        pi[p] = (unsigned char)i;
        pj[p] = (unsigned char)(p - (i * (127 - i)) / 2 + i + 1);
    }

    // --- extract regs -> LDS (waitcnt lands here, hidden by table VALU) ---
    {
        int idx = tid;                     // k parity = idx parity (200 even)
#define EXTRIT(RR, IT)                                                        \
        {                                                                     \
            if (IT < 12 || idx < NSAMP) {                                     \
                sf[idx] = (idx & 1) ? RR.z : RR.x;                            \
            }                                                                 \
            idx += NT;                                                        \
        }
        EXTRIT(r0, 0)  EXTRIT(r1, 1)  EXTRIT(r2, 2)  EXTRIT(r3, 3)
        EXTRIT(r4, 4)  EXTRIT(r5, 5)  EXTRIT(r6, 6)  EXTRIT(r7, 7)
        EXTRIT(r8, 8)  EXTRIT(r9, 9)  EXTRIT(r10, 10) EXTRIT(r11, 11)
        EXTRIT(r12, 12)
#undef EXTRIT
    }
    __syncthreads();

    // --- emit all 2016 pair rows x 50 vec4, nt stores (16KB runs/pass) ---
    const fx4* __restrict__ s4 = reinterpret_cast<const fx4*>(sf); // stride 50
    fx4* __restrict__ ob = out + (size_t)b * (NPAIR * TV4);

    int p  = tid / TV4;
    int t4 = tid - p * TV4;
    for (int v = tid; v < NPAIR * TV4; v += NT) {        // 100800
        fx4 a = s4[pi[p] * TV4 + t4];
        fx4 c = s4[pj[p] * TV4 + t4];
        __builtin_nontemporal_store(a - c, &ob[(size_t)p * TV4 + t4]);
        p += 20;                                 // 1024 = 20*50 + 24
        t4 += 24;
        if (t4 >= TV4) { t4 -= TV4; ++p; }
    }
}

extern "C" void kernel_launch(void* const* d_in, const int* in_sizes, int n_in,
                              void* d_out, int out_size, void* d_ws, size_t ws_size,
                              hipStream_t stream) {
    const float* x = (const float*)d_in[0];
    float* out = (float*)d_out;
    ts_sub_b<<<dim3(NB), dim3(NT), 0, stream>>>((const fx4*)x, (fx4*)out);
}